// Round 1
// 623.874 us; speedup vs baseline: 1.0022x; 1.0022x over previous
//
#include <hip/hip_runtime.h>
#include <hip/hip_bf16.h>

#define BB 128
#define LC 256
#define LE 1024
#define DD 256
#define MM 512

typedef short bf16x8 __attribute__((ext_vector_type(8)));
typedef unsigned short u16x8 __attribute__((ext_vector_type(8)));
typedef unsigned short u16x4 __attribute__((ext_vector_type(4)));
typedef float f32x4 __attribute__((ext_vector_type(4)));

__device__ __forceinline__ float bfu2f(unsigned short u) {
  return __uint_as_float(((unsigned int)u) << 16);
}
__device__ __forceinline__ unsigned short f2bfu(float f) {
  unsigned int x = __float_as_uint(f);
  return (unsigned short)((x + 0x7fffu + ((x >> 16) & 1u)) >> 16);
}

// LDS tile: rows x 32 k (u16), row stride 40, 16B-chunk XOR swizzle.
#define LDST 40
__device__ __forceinline__ int ldsoff(int r, int q) {
  return r * LDST + ((q ^ ((r >> 2) & 3)) << 3);
}

// ---- shared MFMA inner step: 4 waves, each 64x64 = 4x4 tiles of 16x16x32 ----
__device__ __forceinline__ void mma_step(const unsigned short* As, const unsigned short* Bs,
                                         f32x4 (&acc)[4][4], int wm, int wn, int lane) {
  const int lm = lane & 15, quad = lane >> 4;
  bf16x8 a[4], b[4];
#pragma unroll
  for (int i = 0; i < 4; ++i) {
    int r = wm * 64 + i * 16 + lm;
    a[i] = *(const bf16x8*)&As[ldsoff(r, quad)];
    int n = wn * 64 + i * 16 + lm;
    b[i] = *(const bf16x8*)&Bs[ldsoff(n, quad)];
  }
#pragma unroll
  for (int i = 0; i < 4; ++i)
#pragma unroll
    for (int j = 0; j < 4; ++j)
      acc[i][j] = __builtin_amdgcn_mfma_f32_16x16x32_bf16(a[i], b[j], acc[i][j], 0, 0, 0);
}

// ---- generic MFMA tile step with independent row offsets (for fused attn) ----
template <int MT, int NT>
__device__ __forceinline__ void mma_tiles(const unsigned short* As, const unsigned short* Bs,
                                          f32x4 (&acc)[MT][NT], int m0, int n0, int lane) {
  const int lm = lane & 15, quad = lane >> 4;
  bf16x8 a[MT], b[NT];
#pragma unroll
  for (int i = 0; i < MT; ++i)
    a[i] = *(const bf16x8*)&As[ldsoff(m0 + i * 16 + lm, quad)];
#pragma unroll
  for (int j = 0; j < NT; ++j)
    b[j] = *(const bf16x8*)&Bs[ldsoff(n0 + j * 16 + lm, quad)];
#pragma unroll
  for (int i = 0; i < MT; ++i)
#pragma unroll
    for (int j = 0; j < NT; ++j)
      acc[i][j] = __builtin_amdgcn_mfma_f32_16x16x32_bf16(a[i], b[j], acc[i][j], 0, 0, 0);
}

// ---- natural staging: bf16 source rows [r][k], 128x32 tile, 256 threads ----
__device__ __forceinline__ void stage_bf16(unsigned short* S, const unsigned short* g,
                                           long ld, int tid) {
#pragma unroll
  for (int i = 0; i < 2; ++i) {
    int c = tid + i * 256;
    int r = c >> 2, q = c & 3;
    u16x8 v = *(const u16x8*)(g + (long)r * ld + q * 8);
    *(u16x8*)&S[ldsoff(r, q)] = v;
  }
}

// ---- natural staging with fp32 -> bf16 convert (256 threads) ----
__device__ __forceinline__ void stage_f32(unsigned short* S, const float* g, long ld, int tid) {
#pragma unroll
  for (int i = 0; i < 2; ++i) {
    int c = tid + i * 256;
    int r = c >> 2, q = c & 3;
    const float4* p = (const float4*)(g + (long)r * ld + q * 8);
    float4 v0 = p[0], v1 = p[1];
    u16x8 o;
    o[0] = f2bfu(v0.x); o[1] = f2bfu(v0.y); o[2] = f2bfu(v0.z); o[3] = f2bfu(v0.w);
    o[4] = f2bfu(v1.x); o[5] = f2bfu(v1.y); o[6] = f2bfu(v1.z); o[7] = f2bfu(v1.w);
    *(u16x8*)&S[ldsoff(r, q)] = o;
  }
}

// ---- 512-thread staging: 128x32 bf16 tile in one shot ----
__device__ __forceinline__ void stage512(unsigned short* S, const unsigned short* g,
                                         long ld, int tid) {
  int r = tid >> 2, q = tid & 3;
  *(u16x8*)&S[ldsoff(r, q)] = *(const u16x8*)(g + (long)r * ld + q * 8);
}

// ---- 512-thread staging: 256x32 bf16 tile (two shots) ----
__device__ __forceinline__ void stage512x2(unsigned short* S, const unsigned short* g,
                                           long ld, int tid) {
#pragma unroll
  for (int it = 0; it < 2; ++it) {
    int c = tid + it * 512;
    int r = c >> 2, q = c & 3;
    *(u16x8*)&S[ldsoff(r, q)] = *(const u16x8*)(g + (long)r * ld + q * 8);
  }
}

// ---- zero fill ----
__global__ void zero_kernel(float* __restrict__ p, int n) {
  int i = blockIdx.x * 256 + threadIdx.x;
  if (i < n) p[i] = 0.f;
}

// ---- weight transpose+convert ----
__global__ void wconv_kernel(const float* __restrict__ Wa, const float* __restrict__ Wr,
                             unsigned short* __restrict__ WaT, unsigned short* __restrict__ WrT) {
  int i = blockIdx.x * 256 + threadIdx.x;
  if (i < 65536) WaT[i] = f2bfu(Wa[(i & 255) * 256 + (i >> 8)]);
  if (i < 131072) WrT[i] = f2bfu(Wr[(long)(i & 511) * 256 + (i >> 9)]);
}

// ---- fp32 [R][C] -> (a) mask-baked bf16 transpose dstT[C][R], (b) natural bf16 dstN[R][C] ----
__global__ void transT_kernel(const float* __restrict__ src, const int* __restrict__ mask,
                              unsigned short* __restrict__ dstT, unsigned short* __restrict__ dstN,
                              int R, int C) {
  __shared__ unsigned short T[64][72];
  const int tid = threadIdx.x, b = blockIdx.z;
  const int r0 = blockIdx.y * 64, c0 = blockIdx.x * 64;
  const float* s = src + (long)b * R * C;
  const int* mk = mask + (long)b * R;
  unsigned short* dT = dstT + (long)b * R * C;
  unsigned short* dN = dstN + (long)b * R * C;
#pragma unroll
  for (int i = 0; i < 4; ++i) {
    int r = (tid >> 4) + i * 16, c4 = tid & 15;
    float4 v = *(const float4*)(s + (long)(r0 + r) * C + c0 + c4 * 4);
    u16x4 nat;
    nat[0] = f2bfu(v.x); nat[1] = f2bfu(v.y); nat[2] = f2bfu(v.z); nat[3] = f2bfu(v.w);
    *(u16x4*)(dN + (long)(r0 + r) * C + c0 + c4 * 4) = nat;
    float g = mk[r0 + r] ? 1.f : 0.f;
    T[c4 * 4 + 0][r] = f2bfu(v.x * g);
    T[c4 * 4 + 1][r] = f2bfu(v.y * g);
    T[c4 * 4 + 2][r] = f2bfu(v.z * g);
    T[c4 * 4 + 3][r] = f2bfu(v.w * g);
  }
  __syncthreads();
#pragma unroll
  for (int j = 0; j < 2; ++j) {
    int idx = tid * 2 + j;
    int row = idx >> 3, ch = idx & 7;
    *(u16x8*)(dT + (long)(c0 + row) * R + r0 + ch * 8) = *(const u16x8*)&T[row][ch * 8];
  }
}

// ---- proj: out = relu(A @ Wa + ba) -> bf16 ----
__global__ __launch_bounds__(256, 2) void proj_mfma(const float* __restrict__ A,
                                                    const unsigned short* __restrict__ WaT,
                                                    const float* __restrict__ ba,
                                                    unsigned short* __restrict__ out) {
  __shared__ unsigned short As[128 * LDST], Bs[128 * LDST];
  const int tid = threadIdx.x, lane = tid & 63, w = tid >> 6, wm = w >> 1, wn = w & 1;
  const long m0 = (long)blockIdx.y * 128;
  const int n0 = blockIdx.x * 128;
  f32x4 acc[4][4] = {};
  for (int k0 = 0; k0 < DD; k0 += 32) {
    stage_f32(As, A + m0 * DD + k0, DD, tid);
    stage_bf16(Bs, WaT + (long)n0 * DD + k0, DD, tid);
    __syncthreads();
    mma_step(As, Bs, acc, wm, wn, lane);
    __syncthreads();
  }
  const int lm = lane & 15, quad = lane >> 4;
#pragma unroll
  for (int i = 0; i < 4; ++i)
#pragma unroll
    for (int j = 0; j < 4; ++j) {
      int col = n0 + wn * 64 + j * 16 + lm;
      float bias = ba[col];
#pragma unroll
      for (int r = 0; r < 4; ++r) {
        long row = m0 + wm * 64 + i * 16 + quad * 4 + r;
        float v = acc[i][j][r] + bias;
        out[row * DD + col] = f2bfu(v > 0.f ? v : 0.f);
      }
    }
}

// ============================================================================
// Fused attention (criteria side): per (b, Lc-tile of 128) block, loop over
// Le in 8 chunks of 128. For each chunk:
//   S^T = eB_chunk @ cB_tile^T via MFMA (swapped operands => each lane's
//   contiguous acc regs run along Le = the PV contraction axis), exp() in
//   registers, pack u16x4 into the swizzled row-major S-LDS [Lc][Le-k] that
//   mma_tiles reads directly, accumulate asum (em-masked) per-lane, then
//   attc_acc += S_lds @ ehrTm_chunk. Softmax denominator is block-local:
//   the Le loop covers the whole axis. expv/expvT never touch HBM.
// ============================================================================
__global__ __launch_bounds__(512, 2) void attn_c_fused(
    const unsigned short* __restrict__ cB, const unsigned short* __restrict__ eB,
    const unsigned short* __restrict__ ehrTm, const int* __restrict__ em,
    unsigned short* __restrict__ attc) {
  __shared__ unsigned short AB[256 * LDST];   // S-phase: As|Bs halves; PV: 256-row B tile
  __shared__ unsigned short S4[4][128 * LDST];// exp'd scores, 128 Lc x 128 Le (4 k-chunks)
  __shared__ float asum_s[128];
  const int tid = threadIdx.x, lane = tid & 63, w = tid >> 6;
  const int lm = lane & 15, quad = lane >> 4;
  const int wmS = w >> 2, wnS = w & 3;  // S: Le-half(64), Lc-quarter(32)
  const int wm = w >> 2, wn = w & 3;    // PV: Lc-half(64), D-quarter(64)
  // XCD-bijective remap: both Lc-tiles of a batch land on the same XCD L2.
  const int fid = blockIdx.x;             // 256 blocks = 8 xcd * 32
  const int lid = (fid & 7) * 32 + (fid >> 3);
  const int b = lid >> 1, m0 = (lid & 1) * 128;
  unsigned short* As = AB;
  unsigned short* Bs = AB + 128 * LDST;
  const unsigned short* Ag = cB + ((long)b * LC + m0) * DD;
  if (tid < 128) asum_s[tid] = 0.f;
  f32x4 acc[4][4] = {};
  float ap0 = 0.f, ap1 = 0.f;
  __syncthreads();
  for (int ch = 0; ch < 8; ++ch) {
    const unsigned short* Eg = eB + ((long)b * LE + ch * 128) * DD;
    f32x4 accS[4][2] = {};
    for (int k0 = 0; k0 < DD; k0 += 32) {
      stage512(As, Eg + k0, DD, tid);  // A rows = Le chunk
      stage512(Bs, Ag + k0, DD, tid);  // B rows = Lc tile
      __syncthreads();
      mma_tiles<4, 2>(As, Bs, accS, wmS * 64, wnS * 32, lane);  // out[Le][Lc]
      __syncthreads();
    }
    // exp + pack into S-LDS [Lc row][Le k] + masked asum partials
#pragma unroll
    for (int i = 0; i < 4; ++i) {
      const int Le0 = wmS * 64 + i * 16 + quad * 4;  // within chunk; mult of 4
      const int4 m4 = *(const int4*)(em + (long)b * LE + ch * 128 + Le0);
      const float em0 = m4.x ? 1.f : 0.f, em1 = m4.y ? 1.f : 0.f;
      const float em2 = m4.z ? 1.f : 0.f, em3 = m4.w ? 1.f : 0.f;
      const int kk = Le0 >> 5, wi = Le0 & 31;
      const int qq = wi >> 3, sub = wi & 7;  // sub in {0,4} -> 8B aligned
#pragma unroll
      for (int j = 0; j < 2; ++j) {
        const int row = wnS * 32 + j * 16 + lm;  // Lc within tile
        float e0 = __expf(accS[i][j][0]);
        float e1 = __expf(accS[i][j][1]);
        float e2 = __expf(accS[i][j][2]);
        float e3 = __expf(accS[i][j][3]);
        float s = em0 * e0 + em1 * e1 + em2 * e2 + em3 * e3;
        if (j == 0) ap0 += s; else ap1 += s;
        u16x4 pk;
        pk[0] = f2bfu(e0); pk[1] = f2bfu(e1); pk[2] = f2bfu(e2); pk[3] = f2bfu(e3);
        *(u16x4*)&S4[kk][ldsoff(row, qq) + sub] = pk;
      }
    }
    __syncthreads();
    // PV: attc_acc += S_lds[kk] @ ehrTm rows(D=256), k = Le chunk
    for (int kk = 0; kk < 4; ++kk) {
      stage512x2(AB, ehrTm + (long)b * DD * LE + ch * 128 + kk * 32, LE, tid);
      __syncthreads();
      mma_tiles<4, 4>(&S4[kk][0], AB, acc, wm * 64, wn * 64, lane);
      __syncthreads();
    }
  }
  // reduce asum across quads (shfl) and Le-halves (LDS atomic)
  {
    float s = ap0;
    s += __shfl_xor(s, 16); s += __shfl_xor(s, 32);
    if (quad == 0) atomicAdd(&asum_s[wnS * 32 + 0 * 16 + lm], s);
    float t = ap1;
    t += __shfl_xor(t, 16); t += __shfl_xor(t, 32);
    if (quad == 0) atomicAdd(&asum_s[wnS * 32 + 1 * 16 + lm], t);
  }
  __syncthreads();
  float rs[4][4];
#pragma unroll
  for (int i = 0; i < 4; ++i)
#pragma unroll
    for (int r = 0; r < 4; ++r)
      rs[i][r] = 1.f / asum_s[wm * 64 + i * 16 + quad * 4 + r];
#pragma unroll
  for (int i = 0; i < 4; ++i)
#pragma unroll
    for (int j = 0; j < 4; ++j) {
      int col = wn * 64 + j * 16 + lm;
#pragma unroll
      for (int r = 0; r < 4; ++r) {
        int row = wm * 64 + i * 16 + quad * 4 + r;
        attc[((long)b * LC + m0 + row) * DD + col] = f2bfu(acc[i][j][r] * rs[i][r]);
      }
    }
}

// ============================================================================
// Fused attention (ehr side): per (b, Le-tile of 128) block, loop over Lc in
// 2 chunks of 128. S = cB_chunk @ eB_tile^T (natural orientation => lane's
// contiguous regs run along Lc = PV contraction axis); exp -> S^T-LDS
// [Le row][Lc k]; bsum (cm-masked) block-local; atte_acc += S^T @ critTm.
// ============================================================================
__global__ __launch_bounds__(512, 2) void attn_e_fused(
    const unsigned short* __restrict__ cB, const unsigned short* __restrict__ eB,
    const unsigned short* __restrict__ critTm, const int* __restrict__ cm,
    unsigned short* __restrict__ atte) {
  __shared__ unsigned short AB[256 * LDST];
  __shared__ unsigned short S4[4][128 * LDST];
  __shared__ float bsum_s[128];
  const int tid = threadIdx.x, lane = tid & 63, w = tid >> 6;
  const int lm = lane & 15, quad = lane >> 4;
  const int wmS = w >> 2, wnS = w & 3;  // S: Lc-half(64), Le-quarter(32)
  const int wm = w >> 2, wn = w & 3;    // PV: Le-half(64), D-quarter(64)
  const int fid = blockIdx.x;             // 1024 blocks = 8 xcd * 128
  const int lid = (fid & 7) * 128 + (fid >> 3);
  const int b = lid >> 3, n0 = (lid & 7) * 128;  // Le tile
  unsigned short* As = AB;
  unsigned short* Bs = AB + 128 * LDST;
  const unsigned short* Eg = eB + ((long)b * LE + n0) * DD;
  if (tid < 128) bsum_s[tid] = 0.f;
  f32x4 acc[4][4] = {};
  float bp0 = 0.f, bp1 = 0.f;
  __syncthreads();
  for (int ch = 0; ch < 2; ++ch) {
    const unsigned short* Cg = cB + ((long)b * LC + ch * 128) * DD;
    f32x4 accS[4][2] = {};
    for (int k0 = 0; k0 < DD; k0 += 32) {
      stage512(As, Cg + k0, DD, tid);  // A rows = Lc chunk
      stage512(Bs, Eg + k0, DD, tid);  // B rows = Le tile
      __syncthreads();
      mma_tiles<4, 2>(As, Bs, accS, wmS * 64, wnS * 32, lane);  // out[Lc][Le]
      __syncthreads();
    }
#pragma unroll
    for (int i = 0; i < 4; ++i) {
      const int Lc0 = wmS * 64 + i * 16 + quad * 4;
      const int4 m4 = *(const int4*)(cm + (long)b * LC + ch * 128 + Lc0);
      const float cm0 = m4.x ? 1.f : 0.f, cm1 = m4.y ? 1.f : 0.f;
      const float cm2 = m4.z ? 1.f : 0.f, cm3 = m4.w ? 1.f : 0.f;
      const int kk = Lc0 >> 5, wi = Lc0 & 31;
      const int qq = wi >> 3, sub = wi & 7;
#pragma unroll
      for (int j = 0; j < 2; ++j) {
        const int row = wnS * 32 + j * 16 + lm;  // Le within tile
        float e0 = __expf(accS[i][j][0]);
        float e1 = __expf(accS[i][j][1]);
        float e2 = __expf(accS[i][j][2]);
        float e3 = __expf(accS[i][j][3]);
        float s = cm0 * e0 + cm1 * e1 + cm2 * e2 + cm3 * e3;
        if (j == 0) bp0 += s; else bp1 += s;
        u16x4 pk;
        pk[0] = f2bfu(e0); pk[1] = f2bfu(e1); pk[2] = f2bfu(e2); pk[3] = f2bfu(e3);
        *(u16x4*)&S4[kk][ldsoff(row, qq) + sub] = pk;
      }
    }
    __syncthreads();
    for (int kk = 0; kk < 4; ++kk) {
      stage512x2(AB, critTm + (long)b * DD * LC + ch * 128 + kk * 32, LC, tid);
      __syncthreads();
      mma_tiles<4, 4>(&S4[kk][0], AB, acc, wm * 64, wn * 64, lane);
      __syncthreads();
    }
  }
  {
    float s = bp0;
    s += __shfl_xor(s, 16); s += __shfl_xor(s, 32);
    if (quad == 0) atomicAdd(&bsum_s[wnS * 32 + 0 * 16 + lm], s);
    float t = bp1;
    t += __shfl_xor(t, 16); t += __shfl_xor(t, 32);
    if (quad == 0) atomicAdd(&bsum_s[wnS * 32 + 1 * 16 + lm], t);
  }
  __syncthreads();
  float rs[4][4];
#pragma unroll
  for (int i = 0; i < 4; ++i)
#pragma unroll
    for (int r = 0; r < 4; ++r)
      rs[i][r] = 1.f / bsum_s[wm * 64 + i * 16 + quad * 4 + r];
#pragma unroll
  for (int i = 0; i < 4; ++i)
#pragma unroll
    for (int j = 0; j < 4; ++j) {
      int col = wn * 64 + j * 16 + lm;
#pragma unroll
      for (int r = 0; r < 4; ++r) {
        int row = wm * 64 + i * 16 + quad * 4 + r;
        atte[((long)b * LE + n0 + row) * DD + col] = f2bfu(acc[i][j][r] * rs[i][r]);
      }
    }
}

// ---- r = sum_seq relu([att | origB] @ Wr + br), all-bf16 staging ----
__global__ __launch_bounds__(256, 2) void rsum_mfma(const unsigned short* __restrict__ att,
                                                    const unsigned short* __restrict__ origB,
                                                    const unsigned short* __restrict__ WrT,
                                                    const float* __restrict__ br,
                                                    float* __restrict__ rout, int Lseq) {
  __shared__ unsigned short As[128 * LDST], Bs[128 * LDST];
  __shared__ float red[2][128];
  const int tid = threadIdx.x, lane = tid & 63, w = tid >> 6, wm = w >> 1, wn = w & 1;
  const long m0 = (long)blockIdx.y * 128;
  const int n0 = blockIdx.x * 128;
  const int b = (int)(m0 / Lseq);
  f32x4 acc[4][4] = {};
  for (int k0 = 0; k0 < 2 * DD; k0 += 32) {
    if (k0 < DD)
      stage_bf16(As, att + m0 * DD + k0, DD, tid);
    else
      stage_bf16(As, origB + m0 * DD + (k0 - DD), DD, tid);
    stage_bf16(Bs, WrT + (long)n0 * (2 * DD) + k0, 2 * DD, tid);
    __syncthreads();
    mma_step(As, Bs, acc, wm, wn, lane);
    __syncthreads();
  }
  const int lm = lane & 15, quad = lane >> 4;
#pragma unroll
  for (int j = 0; j < 4; ++j) {
    int col = n0 + wn * 64 + j * 16 + lm;
    float bias = br[col];
    float s = 0.f;
#pragma unroll
    for (int i = 0; i < 4; ++i)
#pragma unroll
      for (int r = 0; r < 4; ++r) {
        float v = acc[i][j][r] + bias;
        s += v > 0.f ? v : 0.f;
      }
    s += __shfl_xor(s, 16);
    s += __shfl_xor(s, 32);
    if (quad == 0) red[wm][wn * 64 + j * 16 + lm] = s;
  }
  __syncthreads();
  if (tid < 128)
    atomicAdd(&rout[b * DD + n0 + tid], red[0][tid] + red[1][tid]);
}

// ---- build m = [r1 | r2 | r1*r2 | r1-r2] as bf16 [128][1024] ----
__global__ void mbuild_kernel(const float* __restrict__ r1, const float* __restrict__ r2,
                              unsigned short* __restrict__ mB) {
  int i = blockIdx.x * 256 + threadIdx.x;
  int b = i >> 8, d = i & 255;
  float v1 = r1[i], v2 = r2[i];
  unsigned short* row = mB + (long)b * 1024;
  row[d] = f2bfu(v1);
  row[256 + d] = f2bfu(v2);
  row[512 + d] = f2bfu(v1 * v2);
  row[768 + d] = f2bfu(v1 - v2);
}

// ---- h = relu(m @ Wm + bm): M=128, N=512, K=1024 MFMA GEMM ----
__global__ __launch_bounds__(256, 2) void mlp_mfma(const unsigned short* __restrict__ mB,
                                                   const float* __restrict__ Wm,
                                                   const float* __restrict__ bm,
                                                   float* __restrict__ h) {
  __shared__ unsigned short As[128 * LDST], Bs[128 * LDST];
  const int tid = threadIdx.x, lane = tid & 63, w = tid >> 6, wm = w >> 1, wn = w & 1;
  const int n0 = blockIdx.x * 128;
  f32x4 acc[4][4] = {};
  for (int k0 = 0; k0 < 4 * DD; k0 += 32) {
    stage_bf16(As, mB + k0, 4 * DD, tid);
    {
      const int dcc = tid & 7, er = tid >> 3;
#pragma unroll
      for (int i = 0; i < 4; ++i) {
        int nch = dcc + i * 8;
        float4 v = *(const float4*)(Wm + (long)(k0 + er) * MM + n0 + nch * 4);
        float vv[4] = {v.x, v.y, v.z, v.w};
#pragma unroll
        for (int q = 0; q < 4; ++q)
          Bs[ldsoff(nch * 4 + q, er >> 3) + (er & 7)] = f2bfu(vv[q]);
      }
    }
    __syncthreads();
    mma_step(As, Bs, acc, wm, wn, lane);
    __syncthreads();
  }
  const int lm = lane & 15, quad = lane >> 4;
#pragma unroll
  for (int i = 0; i < 4; ++i)
#pragma unroll
    for (int j = 0; j < 4; ++j) {
      int col = n0 + wn * 64 + j * 16 + lm;
      float bias = bm[col];
#pragma unroll
      for (int r = 0; r < 4; ++r) {
        int row = wm * 64 + i * 16 + quad * 4 + r;
        float v = acc[i][j][r] + bias;
        h[(long)row * MM + col] = v > 0.f ? v : 0.f;
      }
    }
}

// ---- out = h @ Wo + bo ----
__global__ void out3_kernel(const float* __restrict__ h, const float* __restrict__ Wo,
                            const float* __restrict__ bo, float* __restrict__ out) {
  const int b = blockIdx.x, tid = threadIdx.x;
  __shared__ float red[256];
  float a[3] = {0.f, 0.f, 0.f};
  for (int k = tid; k < MM; k += 256) {
    float hv = h[(long)b * MM + k];
    a[0] += hv * Wo[k * 3 + 0];
    a[1] += hv * Wo[k * 3 + 1];
    a[2] += hv * Wo[k * 3 + 2];
  }
#pragma unroll
  for (int o = 0; o < 3; ++o) {
    red[tid] = a[o]; __syncthreads();
    for (int st = 128; st > 0; st >>= 1) {
      if (tid < st) red[tid] += red[tid + st];
      __syncthreads();
    }
    if (tid == 0) out[b * 3 + o] = red[0] + bo[o];
    __syncthreads();
  }
}

extern "C" void kernel_launch(void* const* d_in, const int* in_sizes, int n_in,
                              void* d_out, int out_size, void* d_ws, size_t ws_size,
                              hipStream_t stream) {
  const float* criteria = (const float*)d_in[0];
  const float* ehr      = (const float*)d_in[1];
  const int*   cmask    = (const int*)d_in[2];
  const int*   emask    = (const int*)d_in[3];
  const float* Wa       = (const float*)d_in[4];
  const float* ba       = (const float*)d_in[5];
  const float* Wr       = (const float*)d_in[6];
  const float* br       = (const float*)d_in[7];
  const float* Wm       = (const float*)d_in[8];
  const float* bm       = (const float*)d_in[9];
  const float* Wo       = (const float*)d_in[10];
  const float* bo       = (const float*)d_in[11];
  float* out = (float*)d_out;

  char* ws = (char*)d_ws;
  // Buffer choreography (~337 MB). expv/expvT/asum/bsum eliminated by fusion.
  unsigned short* cB     = (unsigned short*)(ws);               // 16.78 MB
  unsigned short* eB     = (unsigned short*)(ws + 16777216);    // 67.1 MB
  unsigned short* ehrTm  = (unsigned short*)(ws + 83886080);    // 67.1 MB, em-masked ehr^T
  unsigned short* critTm = (unsigned short*)(ws + 150994944);   // 16.78 MB, cm-masked crit^T
  unsigned short* ehrN   = (unsigned short*)(ws + 167772160);   // 67.1 MB natural bf16 ehr
  unsigned short* critN  = (unsigned short*)(ws + 234881024);   // 16.78 MB natural bf16 crit
  unsigned short* attc   = (unsigned short*)(ws + 251658240);   // 16.78 MB
  unsigned short* atteP  = (unsigned short*)(ws + 268435456);   // 67.1 MB
  float* r1   = (float*)(ws + 335544320);                       // 131072 B
  float* r2   = (float*)(ws + 335675392);                       // 131072 B
  unsigned short* WaT = (unsigned short*)(ws + 335806464);      // 131072 B
  unsigned short* WrT = (unsigned short*)(ws + 335937536);      // 262144 B
  unsigned short* mB  = (unsigned short*)(ws + 336199680);      // 262144 B
  float* hbuf         = (float*)(ws + 336461824);               // 262144 B
  // end: 336,723,968 bytes

  dim3 blk(256);
  // zero r1+r2 (contiguous, 65536 floats)
  zero_kernel<<<dim3(256), blk, 0, stream>>>(r1, 65536);
  wconv_kernel<<<dim3(512), blk, 0, stream>>>(Wa, Wr, WaT, WrT);
  transT_kernel<<<dim3(DD / 64, LE / 64, BB), blk, 0, stream>>>(ehr, emask, ehrTm, ehrN, LE, DD);
  transT_kernel<<<dim3(DD / 64, LC / 64, BB), blk, 0, stream>>>(criteria, cmask, critTm, critN, LC, DD);
  proj_mfma<<<dim3(2, (BB * LC) / 128), blk, 0, stream>>>(criteria, WaT, ba, cB);
  proj_mfma<<<dim3(2, (BB * LE) / 128), blk, 0, stream>>>(ehr, WaT, ba, eB);
  attn_c_fused<<<dim3(BB * (LC / 128)), dim3(512), 0, stream>>>(cB, eB, ehrTm, emask, attc);
  attn_e_fused<<<dim3(BB * (LE / 128)), dim3(512), 0, stream>>>(cB, eB, critTm, cmask, atteP);
  rsum_mfma<<<dim3(2, (BB * LC) / 128), blk, 0, stream>>>(attc, critN, WrT, br, r1, LC);
  rsum_mfma<<<dim3(2, (BB * LE) / 128), blk, 0, stream>>>(atteP, ehrN, WrT, br, r2, LE);
  mbuild_kernel<<<dim3(BB), blk, 0, stream>>>(r1, r2, mB);
  mlp_mfma<<<dim3(MM / 128), blk, 0, stream>>>(mB, Wm, bm, hbuf);
  out3_kernel<<<dim3(BB), blk, 0, stream>>>(hbuf, Wo, bo, out);
}